// Round 1
// 135.483 us; speedup vs baseline: 1.0479x; 1.0479x over previous
//
#include <hip/hip_runtime.h>

typedef unsigned int  u32;
typedef unsigned short u16;

typedef __bf16 bf16x8 __attribute__((ext_vector_type(8)));
typedef float  floatx4 __attribute__((ext_vector_type(4)));

#define N_ROWS 256
#define IN_F   8192
#define OUT_F  8320
#define JDIM   128
#define KDIM   16
#define JK     2048

#define BM     256
#define BN     64
#define BK     64
#define WSTRIDE 72   // u16 units; 144 B = 9*16 -> b128-aligned, 2-way banks (free)

#define SLAB_U16   (N_ROWS * JK)      // 524288 u16 per slab
#define JSLICE_U16 (N_ROWS * KDIM)    // 4096 u16 per [j][n][k] slice

typedef const __attribute__((address_space(1))) u32 gu32;
typedef __attribute__((address_space(3))) u32 su32;

__device__ __forceinline__ u16 f2bf(float f) {
    u32 u = __float_as_uint(f);
    return (u16)((u + 0x7fffu + ((u >> 16) & 1u)) >> 16);
}
__device__ __forceinline__ float bf2f(u16 h) { return __uint_as_float(((u32)h) << 16); }

// Kernel A: copy X into out[:, :8192], convert X->bf16 into Xb, zero diversity region of out.
__global__ __launch_bounds__(256) void prep_kernel(const float* __restrict__ X,
                                                   float* __restrict__ out,
                                                   u16* __restrict__ Xb)
{
    int t = blockIdx.x * 256 + threadIdx.x;      // 0..524287, one float4 each
    float4 v = reinterpret_cast<const float4*>(X)[t];
    int row = t >> 11;                           // 2048 float4 per row
    int c4  = t & 2047;
    reinterpret_cast<float4*>(out + (size_t)row * OUT_F)[c4] = v;
    ushort4 b;
    b.x = f2bf(v.x); b.y = f2bf(v.y); b.z = f2bf(v.z); b.w = f2bf(v.w);
    reinterpret_cast<ushort4*>(Xb)[t] = b;
    if (t < 8192) {
        int r2 = t >> 5, j4 = t & 31;            // 32 float4 per 128-wide diversity row
        reinterpret_cast<float4*>(out + (size_t)r2 * OUT_F + IN_F)[j4] = make_float4(0.f, 0.f, 0.f, 0.f);
    }
}

// Kernel B: slab[s] = Xb[256 rows, kslab] * W[kslab, 64 cols] bf16 MFMA, no atomics.
// BM=256 (full M): W is fetched once. Grid (2048/64 = 32 col-blocks, S slabs).
// W staged via 4x dwordx4/thread (wide coalesced), bf16-packed to [col][k] LDS;
// next iter's W register-prefetched AFTER the 2nd barrier so HBM latency overlaps MFMA.
// Epilogue stores slab in [s][j][n][k] layout (j = col>>4, k = col&15) so the
// fused reduce+pairwise kernel reads each j-slice fully coalesced.
__global__ __launch_bounds__(256) void gemm_kernel(const u16* __restrict__ Xb,
                                                   const float* __restrict__ W,
                                                   u16* __restrict__ slabs,
                                                   int kchunk)
{
    __shared__ u16 xs[BM * BK];         // 32 KB, [row][slot*8] XOR-swizzled 16B chunks
    __shared__ u16 wt[BN * WSTRIDE];    // 9 KB,  [col][k] padded

    const int tid  = threadIdx.x;
    const int lane = tid & 63;
    const int wave = tid >> 6;
    const int c0   = blockIdx.x * BN;
    const int s    = blockIdx.y;
    const int k0base = s * kchunk;

    floatx4 acc[4][4] = {};             // wave owns rows wave*64..+63, all 64 cols

    const int xrl = lane >> 3;          // row within 8-row staging group
    const int xgc = (lane & 7) ^ xrl;   // global 16B chunk fetched into slot lane&7
    const int wk  = (tid >> 4) << 2;    // W staging k-quad base: 0,4,...,60
    const int wc  = (tid & 15) << 2;    // W staging col group: 0,4,...,60

    const float* wptr = W + (size_t)(k0base + wk) * JK + c0 + wc;

    // prologue: prefetch iter-0 W tile into registers (4x dwordx4)
    float4 wreg[4];
    #pragma unroll
    for (int r = 0; r < 4; ++r)
        wreg[r] = *(const float4*)(wptr + (size_t)r * JK);

    const int iters = kchunk >> 6;
    for (int it = 0; it < iters; ++it) {
        const int k0 = k0base + it * BK;
        __syncthreads();                // readers of previous tile done

        // --- stage X: each wave its own 64 rows, 8 rows/instr via global_load_lds 16B ---
        #pragma unroll
        for (int g = 0; g < 8; ++g) {
            int rbase = wave * 64 + g * 8;
            const u16* gp = Xb + (size_t)(rbase + xrl) * IN_F + k0 + xgc * 8;
            u32* lp = (u32*)&xs[rbase * BK];          // wave-uniform base; HW adds lane*16B
            __builtin_amdgcn_global_load_lds((gu32*)gp, (su32*)lp, 16, 0, 0);
        }

        // --- W: pack prefetched regs (4 cols x 4 k) -> bf16 [col][k], b64 writes ---
        {
            const float* wr = (const float*)wreg;
            #pragma unroll
            for (int i = 0; i < 4; ++i) {
                u32 lo = (u32)f2bf(wr[0 * 4 + i]) | ((u32)f2bf(wr[1 * 4 + i]) << 16);
                u32 hi = (u32)f2bf(wr[2 * 4 + i]) | ((u32)f2bf(wr[3 * 4 + i]) << 16);
                uint2 v; v.x = lo; v.y = hi;
                *(uint2*)&wt[(wc + i) * WSTRIDE + wk] = v;
            }
        }
        __syncthreads();

        // --- prefetch next iter's W tile; stays in flight across the MFMA section ---
        if (it + 1 < iters) {
            const float* wn = wptr + (size_t)(it + 1) * BK * JK;
            #pragma unroll
            for (int r = 0; r < 4; ++r)
                wreg[r] = *(const float4*)(wn + (size_t)r * JK);
        }

        // --- fragments + MFMA ---
        const int mrow = lane & 15;
        const int q    = lane >> 4;
        #pragma unroll
        for (int h = 0; h < 2; ++h) {
            bf16x8 a[4], b[4];
            #pragma unroll
            for (int rt = 0; rt < 4; ++rt) {
                int rl   = wave * 64 + rt * 16 + mrow;
                int slot = (h * 4 + q) ^ (rl & 7);
                a[rt] = *reinterpret_cast<const bf16x8*>(&xs[rl * BK + slot * 8]);
            }
            #pragma unroll
            for (int ct = 0; ct < 4; ++ct) {
                int col = ct * 16 + mrow;
                b[ct] = *reinterpret_cast<const bf16x8*>(&wt[col * WSTRIDE + (h * 4 + q) * 8]);
            }
            #pragma unroll
            for (int rt = 0; rt < 4; ++rt)
                #pragma unroll
                for (int ct = 0; ct < 4; ++ct)
                    acc[rt][ct] = __builtin_amdgcn_mfma_f32_16x16x32_bf16(a[rt], b[ct], acc[rt][ct], 0, 0, 0);
        }
    }

    // --- epilogue: bf16 stores, [s][j][n][k] layout. D: col=lane&15, row=(lane>>4)*4+reg ---
    // per store instr: 16 consecutive k (32 B contiguous) x 4 row-groups at 128 B stride
    // -> all traffic within 512 B, better than the old 4 KB-row scatter.
    const int qe = lane >> 4;
    const int cl = lane & 15;
    u16* sp = slabs + (size_t)s * SLAB_U16;
    #pragma unroll
    for (int rt = 0; rt < 4; ++rt)
        #pragma unroll
        for (int ct = 0; ct < 4; ++ct) {
            int j = (c0 >> 4) + ct;                  // col>>4 ; col&15 == cl
            #pragma unroll
            for (int r = 0; r < 4; ++r) {
                int row = wave * 64 + rt * 16 + qe * 4 + r;
                sp[(size_t)j * JSLICE_U16 + row * KDIM + cl] = f2bf(acc[rt][ct][r]);
            }
        }
}

// Kernel C (fused reduce + pairwise):
//   thread n of block (j, mq):
//     f[k] = sum_s slab[s][j][n][k]   (coalesced: 256 threads x 32 B = contiguous 8 KB/slab)
//     diversity contribution for m in [mq*64, mq*64+64): atomicAdd.
// The reduced values stay in registers -> no feats intermediate, no reduce kernel.
template<int S>
__global__ __launch_bounds__(256) void fused_rp_kernel(const u16* __restrict__ slabs,
                                                       float* __restrict__ out)
{
    const int j  = blockIdx.x;             // 0..127
    const int mq = blockIdx.y;             // 0..3 -> m chunk of 64
    const int n  = threadIdx.x;

    __shared__ float F[N_ROWS * KDIM];     // 16 KB

    const u16* base = slabs + (size_t)j * JSLICE_U16 + n * KDIM;

    float f[16];
    #pragma unroll
    for (int k = 0; k < 16; ++k) f[k] = 0.f;

    // s-loop in bursts of 4 slabs (8 uint4 in flight) to bound VGPR pressure
    #pragma unroll
    for (int so = 0; so < S; so += 4) {
        uint4 va[4], vb[4];
        #pragma unroll
        for (int i = 0; i < 4; ++i) {
            const u16* p = base + (size_t)(so + i) * SLAB_U16;
            va[i] = *(const uint4*)p;
            vb[i] = *(const uint4*)(p + 8);
        }
        #pragma unroll
        for (int i = 0; i < 4; ++i) {
            const u16* ha = (const u16*)&va[i];
            const u16* hb = (const u16*)&vb[i];
            #pragma unroll
            for (int e = 0; e < 8; ++e) {
                f[e]     += bf2f(ha[e]);
                f[8 + e] += bf2f(hb[e]);
            }
        }
    }

    float4* Fp = (float4*)&F[n * KDIM];
    Fp[0] = make_float4(f[0],  f[1],  f[2],  f[3]);
    Fp[1] = make_float4(f[4],  f[5],  f[6],  f[7]);
    Fp[2] = make_float4(f[8],  f[9],  f[10], f[11]);
    Fp[3] = make_float4(f[12], f[13], f[14], f[15]);
    __syncthreads();

    float accum = 0.f;
    const int m0 = mq * 64;
    #pragma unroll 2
    for (int m = 0; m < 64; ++m) {
        const float* Fm = &F[(m0 + m) * KDIM];   // wave-uniform -> LDS broadcast
        float l1 = 0.f;
        #pragma unroll
        for (int k = 0; k < 16; ++k) l1 += fabsf(f[k] - Fm[k]);
        accum += exp2f(-1.4426950408889634f * l1);
    }
    atomicAdd(&out[(size_t)n * OUT_F + IN_F + j], accum);
}

extern "C" void kernel_launch(void* const* d_in, const int* in_sizes, int n_in,
                              void* d_out, int out_size, void* d_ws, size_t ws_size,
                              hipStream_t stream)
{
    const float* X = (const float*)d_in[0];   // [256, 8192] fp32
    const float* T = (const float*)d_in[1];   // [8192, 128, 16] fp32 = [8192, 2048]
    float* out = (float*)d_out;               // [256, 8320] fp32

    u16* Xb    = (u16*)d_ws;                                // 4 MB bf16 [256,8192]
    u16* slabs = (u16*)((char*)d_ws + (4u << 20));          // S MB bf16 [S,128,256,16]

    int S = 16;                                             // split-K factor
    if (ws_size < (4u << 20) + (size_t)16 * SLAB_U16 * 2) S = 8;
    if (ws_size < (4u << 20) + (size_t)8  * SLAB_U16 * 2) S = 4;
    int kchunk = IN_F / S;

    prep_kernel<<<2048, 256, 0, stream>>>(X, out, Xb);
    gemm_kernel<<<dim3(JK / BN, S), 256, 0, stream>>>(Xb, T, slabs, kchunk);
    if (S == 16)
        fused_rp_kernel<16><<<dim3(JDIM, 4), 256, 0, stream>>>(slabs, out);
    else if (S == 8)
        fused_rp_kernel<8><<<dim3(JDIM, 4), 256, 0, stream>>>(slabs, out);
    else
        fused_rp_kernel<4><<<dim3(JDIM, 4), 256, 0, stream>>>(slabs, out);
}